// Round 2
// baseline (84.234 us; speedup 1.0000x reference)
//
#include <hip/hip_runtime.h>
#include <hip/hip_bf16.h>
#include <math.h>

// Symmetric Hausdorff, B=8, N=M=4096, D=2, fp32.
// Round 7: same plan as Round 6 (merge hk_final into hk_maxred via
// last-block-done), but spelled with __threadfence() + volatile loads —
// this ROCm build has no __hip_atomic_fence/__hip_atomic_load in device code.
// hk_partial is at the fp32 issue floor (~2.6 inst/pair/dir, no fp32 MFMA
// on CDNA4); the 41.7us fillBuffer is harness-fixed. Remaining lever =
// dispatch overhead: 3 kernels -> 2.
// Pipeline: hk_partial (1024 blocks) -> hk_maxred (256 blocks, last block
// performs the final 256->1 reduction and writes out).

#define B 8
#define N 4096
#define TPB 256
#define IB 8              // i-points per thread
#define JC 32             // j-chunks per (b,dir)
#define JTILE (N / JC)    // 128 j-points per block
#define ITILES (N / TPB)  // 16 i-tiles for the reduce stage
#define RED_BLOCKS (2 * B * ITILES)   // 256 blocks in hk_maxred

__global__ __launch_bounds__(TPB) void hk_partial(const float* __restrict__ pred,
                                                  const float* __restrict__ target,
                                                  float* __restrict__ pw,
                                                  unsigned* __restrict__ counter) {
    // Zero the ticket counter for hk_maxred. Kernel-boundary flush makes
    // this visible to the next kernel in stream order.
    if ((blockIdx.x | blockIdx.y | blockIdx.z | threadIdx.x) == 0)
        *counter = 0u;

    const int bx  = blockIdx.x;        // 0..63: [ib: 0..1] x [jc: 0..31]
    const int ib  = bx & 1;
    const int jc  = bx >> 1;
    const int b   = blockIdx.y;
    const int dir = blockIdx.z;

    const float2* __restrict__ P =
        reinterpret_cast<const float2*>(dir == 0 ? pred : target) + (size_t)b * N;
    const float*  __restrict__ Qf =
        (dir == 0 ? target : pred) + (size_t)b * N * 2 + (size_t)jc * JTILE * 2;

    // Stage this block's 128 j-points as 64 float4 (2 points each). 1 KB LDS.
    __shared__ float4 sQ[JTILE / 2];
    if (threadIdx.x < JTILE / 2)
        sQ[threadIdx.x] = reinterpret_cast<const float4*>(Qf)[threadIdx.x];
    __syncthreads();

    // This thread's IB source points (strided by TPB so pw stores coalesce).
    float m2x[IB], m2y[IB], pp[IB], mn[IB];
    const int i0 = ib * (TPB * IB) + threadIdx.x;
    #pragma unroll
    for (int k = 0; k < IB; ++k) {
        float2 p = P[i0 + k * TPB];
        m2x[k] = -2.f * p.x;
        m2y[k] = -2.f * p.y;
        pp[k]  = fmaf(p.x, p.x, p.y * p.y);
        mn[k]  = 3.402823466e38f;
    }

    // min_j(|q|^2 - 2 p.q): per iter 1 broadcast b128 (2 points) + ~42 VALU.
    #pragma unroll 4
    for (int j = 0; j < JTILE / 2; ++j) {
        float4 q = sQ[j];
        float qqa = fmaf(q.x, q.x, q.y * q.y);
        float qqb = fmaf(q.z, q.z, q.w * q.w);
        #pragma unroll
        for (int k = 0; k < IB; ++k) {
            float ta = fmaf(m2x[k], q.x, fmaf(m2y[k], q.y, qqa));
            float tb = fmaf(m2x[k], q.z, fmaf(m2y[k], q.w, qqb));
            mn[k] = fminf(mn[k], fminf(ta, tb));   // v_min3_f32
        }
    }

    // Partial min for this j-chunk, |p|^2 restored. Layout: [dir][b][jc][i].
    float* dst = pw + (size_t)((dir * B + b) * JC + jc) * N;
    #pragma unroll
    for (int k = 0; k < IB; ++k)
        dst[i0 + k * TPB] = mn[k] + pp[k];
}

// One block per (i-tile, b, dir): min over 32 jc (coalesced), block max-reduce,
// write to a private slot. Last block to finish (device-scope ticket) performs
// the final 256 -> 1 reduction and writes the scalar output.
__global__ __launch_bounds__(TPB) void hk_maxred(const float* __restrict__ pw,
                                                 float* __restrict__ pw2,
                                                 unsigned* __restrict__ counter,
                                                 float* __restrict__ out) {
    const int tile = blockIdx.x;
    const int b    = blockIdx.y;
    const int dir  = blockIdx.z;
    const int t    = threadIdx.x;

    const float* base = pw + (size_t)((dir * B + b) * JC) * N + tile * TPB + t;
    float mnv = base[0];
    #pragma unroll
    for (int jc = 1; jc < JC; ++jc) mnv = fminf(mnv, base[(size_t)jc * N]);

    float mx = mnv;
    #pragma unroll
    for (int off = 32; off > 0; off >>= 1)
        mx = fmaxf(mx, __shfl_down(mx, off, 64));

    __shared__ float sred[TPB / 64];
    __shared__ int lastFlag;
    if ((t & 63) == 0) sred[t >> 6] = mx;
    __syncthreads();
    if (t == 0) {
        float bm = sred[0];
        #pragma unroll
        for (int w = 1; w < TPB / 64; ++w) bm = fmaxf(bm, sred[w]);
        pw2[(dir * B + b) * ITILES + tile] = bm;   // [dir][b][tile]
        __threadfence();                            // release pw2 store (device scope)
        unsigned ticket = atomicAdd(counter, 1u);   // device-scope by default
        lastFlag = (ticket == RED_BLOCKS - 1) ? 1 : 0;
    }
    __syncthreads();
    if (!lastFlag) return;

    // Last block: all 256 pw2 slots were released (store -> threadfence ->
    // atomicAdd) before our ticket returned last. Acquire with a fence and
    // read via volatile (sc0-coherent loads, no stale cache lines).
    __threadfence();
    const volatile float* vpw2 = pw2;
    __shared__ float h2[2 * B];
    if (t < 2 * B) {
        float m2 = vpw2[t * ITILES];
        #pragma unroll
        for (int k = 1; k < ITILES; ++k)
            m2 = fmaxf(m2, vpw2[t * ITILES + k]);
        h2[t] = m2;
    }
    __syncthreads();
    if (t == 0) {
        float s = 0.f;
        #pragma unroll
        for (int bb = 0; bb < B; ++bb)
            s += sqrtf(fmaxf(fmaxf(h2[bb], h2[B + bb]), 0.f));
        out[0] = s * (1.0f / B);
    }
}

extern "C" void kernel_launch(void* const* d_in, const int* in_sizes, int n_in,
                              void* d_out, int out_size, void* d_ws, size_t ws_size,
                              hipStream_t stream) {
    const float* pred   = (const float*)d_in[0];
    const float* target = (const float*)d_in[1];
    float* out = (float*)d_out;
    float* pw  = (float*)d_ws;                         // 2*8*32*4096 floats = 8 MB
    float* pw2 = pw + (size_t)2 * B * JC * N;          // 256 floats
    unsigned* counter = (unsigned*)(pw2 + RED_BLOCKS); // 4 bytes

    dim3 g1(64, B, 2);           // 1024 blocks -> 4 blocks/CU, 16 waves/CU
    hk_partial<<<g1, TPB, 0, stream>>>(pred, target, pw, counter);
    dim3 g2(ITILES, B, 2);       // 256 blocks; last one finishes the job
    hk_maxred<<<g2, TPB, 0, stream>>>(pw, pw2, counter, out);
}

// Round 3
// 78.628 us; speedup vs baseline: 1.0713x; 1.0713x over previous
//
#include <hip/hip_runtime.h>
#include <hip/hip_bf16.h>
#include <math.h>

// Symmetric Hausdorff, B=8, N=M=4096, D=2, fp32.
// Round 8: REVERT Round-6/7 merge (per-block __threadfence on gfx950 forces
// cross-XCD L2 writeback in all 256 reducer blocks -> +6.5us; a kernel
// boundary does that flush once). Back to the 3-kernel R5 pipeline, one
// change: JC 32 -> 16.
//   - pw halves (8 -> 4 MB): hk_maxred reads half, min chain 32 -> 16,
//     hk_partial stores half. hk_partial total VALU identical (work just
//     redistributed: 512 blocks, 2 blocks/CU, 8 waves/CU; IB=8 chains keep
//     VALU fed at 2 waves/SIMD).
//   - hk_partial stays at the fp32 issue floor (~2.5 inst/pair/dir; no fp32
//     MFMA on CDNA4, v_pk_fma_f32 has no rate gain on SIMD-32 gfx950).
// The ~41.7us fillBuffer in every profile is the harness poisoning the
// 256 MiB workspace inside the timed window — fixed cost, not ours.
// Pipeline: hk_partial (512) -> hk_maxred (256) -> hk_final (1).

#define B 8
#define N 4096
#define TPB 256
#define IB 8              // i-points per thread
#define JC 16             // j-chunks per (b,dir)
#define JTILE (N / JC)    // 256 j-points per block
#define ITILES (N / TPB)  // 16 i-tiles for the reduce stage

__global__ __launch_bounds__(TPB) void hk_partial(const float* __restrict__ pred,
                                                  const float* __restrict__ target,
                                                  float* __restrict__ pw) {
    const int bx  = blockIdx.x;        // 0..31: [ib: 0..1] x [jc: 0..15]
    const int ib  = bx & 1;
    const int jc  = bx >> 1;
    const int b   = blockIdx.y;
    const int dir = blockIdx.z;

    const float2* __restrict__ P =
        reinterpret_cast<const float2*>(dir == 0 ? pred : target) + (size_t)b * N;
    const float*  __restrict__ Qf =
        (dir == 0 ? target : pred) + (size_t)b * N * 2 + (size_t)jc * JTILE * 2;

    // Stage this block's 256 j-points as 128 float4 (2 points each). 2 KB LDS.
    __shared__ float4 sQ[JTILE / 2];
    if (threadIdx.x < JTILE / 2)
        sQ[threadIdx.x] = reinterpret_cast<const float4*>(Qf)[threadIdx.x];
    __syncthreads();

    // This thread's IB source points (strided by TPB so pw stores coalesce).
    float m2x[IB], m2y[IB], pp[IB], mn[IB];
    const int i0 = ib * (TPB * IB) + threadIdx.x;
    #pragma unroll
    for (int k = 0; k < IB; ++k) {
        float2 p = P[i0 + k * TPB];
        m2x[k] = -2.f * p.x;
        m2y[k] = -2.f * p.y;
        pp[k]  = fmaf(p.x, p.x, p.y * p.y);
        mn[k]  = 3.402823466e38f;
    }

    // min_j(|q|^2 - 2 p.q): per iter 1 broadcast b128 (2 points) + ~42 VALU.
    #pragma unroll 4
    for (int j = 0; j < JTILE / 2; ++j) {
        float4 q = sQ[j];
        float qqa = fmaf(q.x, q.x, q.y * q.y);
        float qqb = fmaf(q.z, q.z, q.w * q.w);
        #pragma unroll
        for (int k = 0; k < IB; ++k) {
            float ta = fmaf(m2x[k], q.x, fmaf(m2y[k], q.y, qqa));
            float tb = fmaf(m2x[k], q.z, fmaf(m2y[k], q.w, qqb));
            mn[k] = fminf(mn[k], fminf(ta, tb));   // v_min3_f32
        }
    }

    // Partial min for this j-chunk, |p|^2 restored. Layout: [dir][b][jc][i].
    float* dst = pw + (size_t)((dir * B + b) * JC + jc) * N;
    #pragma unroll
    for (int k = 0; k < IB; ++k)
        dst[i0 + k * TPB] = mn[k] + pp[k];
}

// One block per (i-tile, b, dir): min over 16 jc (coalesced), block max-reduce,
// write to a private slot — no atomics, no init required.
__global__ __launch_bounds__(TPB) void hk_maxred(const float* __restrict__ pw,
                                                 float* __restrict__ pw2) {
    const int tile = blockIdx.x;
    const int b    = blockIdx.y;
    const int dir  = blockIdx.z;
    const int t    = threadIdx.x;

    const float* base = pw + (size_t)((dir * B + b) * JC) * N + tile * TPB + t;
    float mnv = base[0];
    #pragma unroll
    for (int jc = 1; jc < JC; ++jc) mnv = fminf(mnv, base[(size_t)jc * N]);

    float mx = mnv;
    #pragma unroll
    for (int off = 32; off > 0; off >>= 1)
        mx = fmaxf(mx, __shfl_down(mx, off, 64));

    __shared__ float sred[TPB / 64];
    if ((t & 63) == 0) sred[t >> 6] = mx;
    __syncthreads();
    if (t == 0) {
        float bm = sred[0];
        #pragma unroll
        for (int w = 1; w < TPB / 64; ++w) bm = fmaxf(bm, sred[w]);
        pw2[(dir * B + b) * ITILES + tile] = bm;   // [dir][b][tile]
    }
}

// Single block: 256 slots -> 16 (dir,b) maxes -> mean over b of sqrt(max(dirs)).
__global__ __launch_bounds__(64) void hk_final(const float* __restrict__ pw2,
                                               float* __restrict__ out) {
    const int t = threadIdx.x;
    __shared__ float h2[2 * B];
    if (t < 2 * B) {
        float mx = pw2[t * ITILES];
        #pragma unroll
        for (int k = 1; k < ITILES; ++k) mx = fmaxf(mx, pw2[t * ITILES + k]);
        h2[t] = mx;
    }
    __syncthreads();
    if (t == 0) {
        float s = 0.f;
        #pragma unroll
        for (int b = 0; b < B; ++b)
            s += sqrtf(fmaxf(fmaxf(h2[b], h2[B + b]), 0.f));
        out[0] = s * (1.0f / B);
    }
}

extern "C" void kernel_launch(void* const* d_in, const int* in_sizes, int n_in,
                              void* d_out, int out_size, void* d_ws, size_t ws_size,
                              hipStream_t stream) {
    const float* pred   = (const float*)d_in[0];
    const float* target = (const float*)d_in[1];
    float* out = (float*)d_out;
    float* pw  = (float*)d_ws;                       // 2*8*16*4096 floats = 4 MB
    float* pw2 = (float*)((char*)d_ws + (size_t)2 * B * JC * N * sizeof(float)); // 256 floats

    dim3 g1(32, B, 2);           // 512 blocks -> 2 blocks/CU, 8 waves/CU
    hk_partial<<<g1, TPB, 0, stream>>>(pred, target, pw);
    dim3 g2(ITILES, B, 2);       // 256 blocks
    hk_maxred<<<g2, TPB, 0, stream>>>(pw, pw2);
    hk_final<<<1, 64, 0, stream>>>(pw2, out);
}